// Round 9
// baseline (575.375 us; speedup 1.0000x reference)
//
#include <hip/hip_runtime.h>

#define NUSERS  200000
#define NMOVIES 200000
#define NROWS   200000
#define NROWS3  (3 * NROWS)
#define CAP     18                      // bucket capacity per dst (Poisson(5))
#define OVF_MAX 4096
#define EDGE_GRID 2048

typedef __attribute__((ext_vector_type(8))) short bf16x8;
typedef __attribute__((ext_vector_type(4))) float f32x4;

// ---------------------------------------------------------------------------
// K1 (fused hist+scatter): capped buckets, one returning atomic per slot.
//   arr0: um user-side  (key a, store b)
//   arr1: um movie-side (key b, store a)
//   arr2: me entity-agg (key d, store s)
// Overflow (w >= CAP) pushed to a tiny list, fixed up exactly later.
// ---------------------------------------------------------------------------
__global__ __launch_bounds__(256) void bucket_kernel(
    const int* __restrict__ um, const int* __restrict__ me,
    int* __restrict__ cnt_all,          // [3][NROWS], zeroed
    int* __restrict__ bk_all,           // [3][NROWS*CAP]
    int* __restrict__ ovf_meta,         // [0] = count, zeroed
    int* __restrict__ ovf_list,         // [OVF_MAX][2] = (arr<<18|dst, src)
    int E_um, int E_me)
{
    int* cnt_u = cnt_all;
    int* cnt_m = cnt_all + NROWS;
    int* cnt_e = cnt_all + 2 * NROWS;
    int* bk_u = bk_all;
    int* bk_m = bk_all + (size_t)NROWS * CAP;
    int* bk_e = bk_all + (size_t)2 * NROWS * CAP;
    const int total = E_um + E_me;
    for (int t = blockIdx.x * blockDim.x + threadIdx.x; t < total;
         t += gridDim.x * blockDim.x) {
        if (t < E_um) {
            const int a = um[t];
            const int b = um[E_um + t];
            const int w0 = atomicAdd(&cnt_u[a], 1);
            if (w0 < CAP) {
                bk_u[(size_t)a * CAP + w0] = b;
            } else {
                const int i = atomicAdd(ovf_meta, 1);
                if (i < OVF_MAX) { ovf_list[2*i] = (0 << 18) | a; ovf_list[2*i+1] = b; }
            }
            const int w1 = atomicAdd(&cnt_m[b], 1);
            if (w1 < CAP) {
                bk_m[(size_t)b * CAP + w1] = a;
            } else {
                const int i = atomicAdd(ovf_meta, 1);
                if (i < OVF_MAX) { ovf_list[2*i] = (1 << 18) | b; ovf_list[2*i+1] = a; }
            }
        } else {
            const int e = t - E_um;
            const int s = me[e];
            const int d = me[E_me + e];
            const int w2 = atomicAdd(&cnt_e[d], 1);
            if (w2 < CAP) {
                bk_e[(size_t)d * CAP + w2] = s;
            } else {
                const int i = atomicAdd(ovf_meta, 1);
                if (i < OVF_MAX) { ovf_list[2*i] = (2 << 18) | d; ovf_list[2*i+1] = s; }
            }
        }
    }
}

// ---------------------------------------------------------------------------
// K2: gather-accumulate. Wave per dst row, lane = channel. Zero atomics.
// bucket base = r*CAP; c = min(cnt[r], CAP).
// ---------------------------------------------------------------------------
__global__ __launch_bounds__(256) void gather_kernel(
    const int* __restrict__ bucket,
    const float* __restrict__ x,
    const int* __restrict__ cnt,
    float* __restrict__ outbase,   // row stride 128 floats
    int out_off, int nrows)
{
    const int lane = threadIdx.x & 63;
    const int wid = __builtin_amdgcn_readfirstlane(
        (blockIdx.x * blockDim.x + threadIdx.x) >> 6);
    const int nw = (gridDim.x * blockDim.x) >> 6;
    const int rpw = (nrows + nw - 1) / nw;
    const int r0 = wid * rpw;
    const int r1 = min(r0 + rpw, nrows);
    for (int r = r0; r < r1; ++r) {
        const int c = min(cnt[r], CAP);
        const int base = r * CAP;
        float acc0 = 0.f, acc1 = 0.f, acc2 = 0.f, acc3 = 0.f;
        int j = 0;
        for (; j + 4 <= c; j += 4) {
            const int s0 = bucket[base + j];
            const int s1 = bucket[base + j + 1];
            const int s2 = bucket[base + j + 2];
            const int s3 = bucket[base + j + 3];
            acc0 += x[(size_t)s0 * 64 + lane];
            acc1 += x[(size_t)s1 * 64 + lane];
            acc2 += x[(size_t)s2 * 64 + lane];
            acc3 += x[(size_t)s3 * 64 + lane];
        }
        for (; j < c; ++j) {
            const int s0 = bucket[base + j];
            acc0 += x[(size_t)s0 * 64 + lane];
        }
        outbase[(size_t)r * 128 + out_off + lane] = (acc0 + acc1) + (acc2 + acc3);
    }
}

// ---------------------------------------------------------------------------
// K3: overflow fixup (runs after gathers, before finalize). One wave/entry.
// Adds x[src] into the gathered sum location with exact f32 atomics.
// ---------------------------------------------------------------------------
__global__ __launch_bounds__(256) void fixup_kernel(
    const int* __restrict__ ovf_meta,
    const int* __restrict__ ovf_list,
    const float* __restrict__ user_x,
    const float* __restrict__ movie_x,
    const float* __restrict__ entity_x,
    float* __restrict__ out_user,
    float* __restrict__ out_movie)
{
    const int n = min(ovf_meta[0], OVF_MAX);
    const int lane = threadIdx.x & 63;
    const int wv = (blockIdx.x * blockDim.x + threadIdx.x) >> 6;
    const int nw = (gridDim.x * blockDim.x) >> 6;
    for (int i = wv; i < n; i += nw) {
        const int key = ovf_list[2 * i];
        const int src = ovf_list[2 * i + 1];
        const int arr = key >> 18;
        const int dst = key & 0x3FFFF;
        if (arr == 0) {
            atomicAdd(&out_user[(size_t)dst * 128 + 64 + lane],
                      user_x[(size_t)src * 64 + lane]);
        } else if (arr == 1) {
            atomicAdd(&out_movie[(size_t)dst * 128 + 64 + lane],
                      movie_x[(size_t)src * 64 + lane]);
        } else {
            atomicAdd(&out_movie[(size_t)dst * 128 + lane],
                      entity_x[(size_t)src * 64 + lane]);
        }
    }
}

// ---------------------------------------------------------------------------
// Prep: split W_cat = [W1;W2;Wrel;Wroot] (256x64) into bf16 hi/lo, stored
// pre-swizzled for the fragment mapping
//   frag f = (s*4 + t)*64 + lane, elem j:  k = 32s + 8*(lane>>4) + j,
//   col = 16t + (lane&15)
// A-frags use the same k-mapping, so any consistent k-permutation cancels.
// ---------------------------------------------------------------------------
__global__ __launch_bounds__(256) void bsplit_kernel(
    const float* __restrict__ W1, const float* __restrict__ W2,
    const float* __restrict__ Wrel, const float* __restrict__ Wroot,
    unsigned short* __restrict__ BH, unsigned short* __restrict__ BL)
{
    const int idx = blockIdx.x * blockDim.x + threadIdx.x;  // element index
    if (idx >= 8 * 4 * 64 * 8) return;
    const int j = idx & 7;
    const int f = idx >> 3;
    const int l = f & 63;
    const int t = (f >> 6) & 3;
    const int s = f >> 8;
    const int k = 32 * s + 8 * (l >> 4) + j;
    const int col = 16 * t + (l & 15);
    const float* Wsrc;
    switch (k >> 6) {
        case 0:  Wsrc = W1;    break;
        case 1:  Wsrc = W2;    break;
        case 2:  Wsrc = Wrel;  break;
        default: Wsrc = Wroot; break;
    }
    const float v = Wsrc[(k & 63) * 64 + col];
    const unsigned int bits = __float_as_uint(v);
    const unsigned short h = (unsigned short)(bits >> 16);
    const float rem = v - __uint_as_float((unsigned)h << 16);
    BH[idx] = h;
    BL[idx] = (unsigned short)(__float_as_uint(rem) >> 16);
}

// ---- bf16x3 split helpers (all static indexing) ----
__device__ __forceinline__ short bf_hi(float v, float& rem) {
    const unsigned int b = __float_as_uint(v);
    const unsigned short h = (unsigned short)(b >> 16);
    rem = v - __uint_as_float((unsigned)h << 16);
    return (short)h;
}
__device__ __forceinline__ short bf_tr(float v) {
    return (short)(__float_as_uint(v) >> 16);
}
__device__ __forceinline__ void split8(float4 q0, float4 q1,
                                       bf16x8& Ah, bf16x8& Al) {
    float r0, r1, r2, r3, r4, r5, r6, r7;
    Ah[0] = bf_hi(q0.x, r0); Ah[1] = bf_hi(q0.y, r1);
    Ah[2] = bf_hi(q0.z, r2); Ah[3] = bf_hi(q0.w, r3);
    Ah[4] = bf_hi(q1.x, r4); Ah[5] = bf_hi(q1.y, r5);
    Ah[6] = bf_hi(q1.z, r6); Ah[7] = bf_hi(q1.w, r7);
    Al[0] = bf_tr(r0); Al[1] = bf_tr(r1); Al[2] = bf_tr(r2); Al[3] = bf_tr(r3);
    Al[4] = bf_tr(r4); Al[5] = bf_tr(r5); Al[6] = bf_tr(r6); Al[7] = bf_tr(r7);
}

#define MFMA3(acc, Ah, Al, Bh, Bl)                                           \
    acc = __builtin_amdgcn_mfma_f32_16x16x32_bf16(Ah, Bh, acc, 0, 0, 0);     \
    acc = __builtin_amdgcn_mfma_f32_16x16x32_bf16(Al, Bh, acc, 0, 0, 0);     \
    acc = __builtin_amdgcn_mfma_f32_16x16x32_bf16(Ah, Bl, acc, 0, 0, 0);

// ---------------------------------------------------------------------------
// Finalize users via MFMA. Block = 4 waves, 64 rows; wave = 16 rows.
// ---------------------------------------------------------------------------
__global__ __launch_bounds__(256) void finalize_user_mfma(
    const float* __restrict__ user_x,
    const int* __restrict__ cnt_u,
    const float* __restrict__ b1, const float* __restrict__ b2,
    const unsigned short* __restrict__ BH,
    const unsigned short* __restrict__ BL,
    float* out_user)
{
    const int lane = threadIdx.x & 63;
    const int wv = threadIdx.x >> 6;
    const int sub = lane & 15, grp = lane >> 4;
    const int rbase = blockIdx.x * 64 + wv * 16;
    const int myrow = rbase + sub;

    f32x4 acc0 = {0.f, 0.f, 0.f, 0.f}, acc1 = acc0, acc2 = acc0, acc3 = acc0;

#pragma unroll
    for (int s = 0; s < 4; ++s) {
        float4 q0, q1;
        if (s < 2) {
            const float* p = out_user + (size_t)myrow * 128 + 64 + 32 * s + 8 * grp;
            q0 = *(const float4*)p;
            q1 = *(const float4*)(p + 4);
        } else {
            const int off = 32 * (s - 2) + 8 * grp;
            const float* ps = out_user + (size_t)myrow * 128 + 64 + off;
            const float* px = user_x + (size_t)myrow * 64 + off;
            const float4 s0 = *(const float4*)ps, s1 = *(const float4*)(ps + 4);
            const float4 x0 = *(const float4*)px, x1 = *(const float4*)(px + 4);
            q0.x = s0.x * x0.x; q0.y = s0.y * x0.y;
            q0.z = s0.z * x0.z; q0.w = s0.w * x0.w;
            q1.x = s1.x * x1.x; q1.y = s1.y * x1.y;
            q1.z = s1.z * x1.z; q1.w = s1.w * x1.w;
        }
        bf16x8 Ah, Al;
        split8(q0, q1, Ah, Al);
#pragma unroll
        for (int t = 0; t < 4; ++t) {
            const int fo = ((s * 4 + t) * 64 + lane) * 8;
            const bf16x8 Bh = *(const bf16x8*)(BH + fo);
            const bf16x8 Bl = *(const bf16x8*)(BL + fo);
            if (t == 0) { MFMA3(acc0, Ah, Al, Bh, Bl) }
            else if (t == 1) { MFMA3(acc1, Ah, Al, Bh, Bl) }
            else if (t == 2) { MFMA3(acc2, Ah, Al, Bh, Bl) }
            else { MFMA3(acc3, Ah, Al, Bh, Bl) }
        }
    }

#pragma unroll
    for (int i = 0; i < 4; ++i) {
        const int row = rbase + 4 * i + grp;
        const float4 xv = *(const float4*)(user_x + (size_t)row * 64 + sub * 4);
        *(float4*)(out_user + (size_t)row * 128 + sub * 4) = xv;
    }

    // epilogue: C/D layout col = lane&15, row = 4*(lane>>4) + reg
#pragma unroll
    for (int t = 0; t < 4; ++t) {
        const int col = 16 * t + sub;
        const float bb = b1[col] + b2[col];
        const f32x4 a = (t == 0) ? acc0 : (t == 1) ? acc1 : (t == 2) ? acc2 : acc3;
#pragma unroll
        for (int r = 0; r < 4; ++r) {
            const int row = rbase + 4 * grp + r;
            out_user[(size_t)row * 128 + 64 + col] =
                a[r] + (float)cnt_u[row] * bb;
        }
    }
}

// ---------------------------------------------------------------------------
// Finalize movies via MFMA. K=256: [S1, x.S1, Se/ce, ex] @ [W1;W2;Wrel;Wroot]
// ---------------------------------------------------------------------------
__global__ __launch_bounds__(256) void finalize_movie_mfma(
    const float* __restrict__ movie_x,
    const float* __restrict__ entity_x,
    const int* __restrict__ cnt_m, const int* __restrict__ cnt_e,
    const float* __restrict__ b1, const float* __restrict__ b2,
    const float* __restrict__ brgcn,
    const unsigned short* __restrict__ BH,
    const unsigned short* __restrict__ BL,
    float* out_movie)
{
    const int lane = threadIdx.x & 63;
    const int wv = threadIdx.x >> 6;
    const int sub = lane & 15, grp = lane >> 4;
    const int rbase = blockIdx.x * 64 + wv * 16;
    const int myrow = rbase + sub;
    const float invce = 1.0f / fmaxf((float)cnt_e[myrow], 1.0f);

    f32x4 acc0 = {0.f, 0.f, 0.f, 0.f}, acc1 = acc0, acc2 = acc0, acc3 = acc0;

#pragma unroll
    for (int s = 0; s < 8; ++s) {
        float4 q0, q1;
        if (s < 2) {
            const float* p = out_movie + (size_t)myrow * 128 + 64 + 32 * s + 8 * grp;
            q0 = *(const float4*)p;
            q1 = *(const float4*)(p + 4);
        } else if (s < 4) {
            const int off = 32 * (s - 2) + 8 * grp;
            const float* ps = out_movie + (size_t)myrow * 128 + 64 + off;
            const float* px = movie_x + (size_t)myrow * 64 + off;
            const float4 s0 = *(const float4*)ps, s1 = *(const float4*)(ps + 4);
            const float4 x0 = *(const float4*)px, x1 = *(const float4*)(px + 4);
            q0.x = s0.x * x0.x; q0.y = s0.y * x0.y;
            q0.z = s0.z * x0.z; q0.w = s0.w * x0.w;
            q1.x = s1.x * x1.x; q1.y = s1.y * x1.y;
            q1.z = s1.z * x1.z; q1.w = s1.w * x1.w;
        } else if (s < 6) {
            const float* p = out_movie + (size_t)myrow * 128 + 32 * (s - 4) + 8 * grp;
            const float4 e0 = *(const float4*)p, e1 = *(const float4*)(p + 4);
            q0.x = e0.x * invce; q0.y = e0.y * invce;
            q0.z = e0.z * invce; q0.w = e0.w * invce;
            q1.x = e1.x * invce; q1.y = e1.y * invce;
            q1.z = e1.z * invce; q1.w = e1.w * invce;
        } else {
            const float* p = entity_x + (size_t)myrow * 64 + 32 * (s - 6) + 8 * grp;
            q0 = *(const float4*)p;
            q1 = *(const float4*)(p + 4);
        }
        bf16x8 Ah, Al;
        split8(q0, q1, Ah, Al);
#pragma unroll
        for (int t = 0; t < 4; ++t) {
            const int fo = ((s * 4 + t) * 64 + lane) * 8;
            const bf16x8 Bh = *(const bf16x8*)(BH + fo);
            const bf16x8 Bl = *(const bf16x8*)(BL + fo);
            if (t == 0) { MFMA3(acc0, Ah, Al, Bh, Bl) }
            else if (t == 1) { MFMA3(acc1, Ah, Al, Bh, Bl) }
            else if (t == 2) { MFMA3(acc2, Ah, Al, Bh, Bl) }
            else { MFMA3(acc3, Ah, Al, Bh, Bl) }
        }
    }

#pragma unroll
    for (int i = 0; i < 4; ++i) {
        const int row = rbase + 4 * i + grp;
        const float4 xv = *(const float4*)(movie_x + (size_t)row * 64 + sub * 4);
        *(float4*)(out_movie + (size_t)row * 128 + sub * 4) = xv;
    }

#pragma unroll
    for (int t = 0; t < 4; ++t) {
        const int col = 16 * t + sub;
        const float bb = b1[col] + b2[col];
        const float br = brgcn[col];
        const f32x4 a = (t == 0) ? acc0 : (t == 1) ? acc1 : (t == 2) ? acc2 : acc3;
#pragma unroll
        for (int r = 0; r < 4; ++r) {
            const int row = rbase + 4 * grp + r;
            out_movie[(size_t)row * 128 + 64 + col] =
                a[r] + (float)cnt_m[row] * bb + br;
        }
    }
}

extern "C" void kernel_launch(void* const* d_in, const int* in_sizes, int n_in,
                              void* d_out, int out_size, void* d_ws, size_t ws_size,
                              hipStream_t stream)
{
    const float* user_x   = (const float*)d_in[0];
    const float* movie_x  = (const float*)d_in[1];
    const float* entity_x = (const float*)d_in[2];
    const int*   um       = (const int*)d_in[3];
    const int*   me       = (const int*)d_in[4];
    const float* W1       = (const float*)d_in[5];
    const float* b1       = (const float*)d_in[6];
    const float* W2       = (const float*)d_in[7];
    const float* b2       = (const float*)d_in[8];
    const float* Wrel     = (const float*)d_in[9];
    const float* Wroot    = (const float*)d_in[10];
    const float* brgcn    = (const float*)d_in[11];

    const int E_um = in_sizes[3] / 2;
    const int E_me = in_sizes[4] / 2;

    float* out_user  = (float*)d_out;                         // [NUSERS, 128]
    float* out_movie = out_user + (size_t)NUSERS * 128;       // [NMOVIES, 128]

    // Workspace layout (ints)
    int* cnt_all  = (int*)d_ws;                        // [3][NROWS]  - zeroed
    int* ovf_meta = cnt_all + NROWS3;                  // [2]         - zeroed
    int* ovf_list = ovf_meta + 2;                      // [OVF_MAX][2]
    int* bk_all   = ovf_list + 2 * OVF_MAX;            // [3][NROWS*CAP]
    uintptr_t bp = (uintptr_t)(bk_all + (size_t)3 * NROWS * CAP);
    bp = (bp + 63) & ~(uintptr_t)63;
    unsigned short* BH = (unsigned short*)bp;          // [16384]
    unsigned short* BL = BH + 16384;                   // [16384]

    int* cnt_u = cnt_all;
    int* cnt_m = cnt_all + NROWS;
    int* cnt_e = cnt_all + 2 * NROWS;
    int* bk_u = bk_all;
    int* bk_m = bk_all + (size_t)NROWS * CAP;
    int* bk_e = bk_all + (size_t)2 * NROWS * CAP;

    // Zero cnt tables + overflow counter (2.4 MB).
    hipMemsetAsync(cnt_all, 0, (NROWS3 + 2) * sizeof(int), stream);

    bsplit_kernel<<<64, 256, 0, stream>>>(W1, W2, Wrel, Wroot, BH, BL);
    bucket_kernel<<<EDGE_GRID, 256, 0, stream>>>(um, me, cnt_all, bk_all,
                                                 ovf_meta, ovf_list, E_um, E_me);

    // Gather phases (stream-sequential so each side's x-table stays L3-hot).
    gather_kernel<<<2048, 256, 0, stream>>>(bk_e, entity_x, cnt_e,
                                            out_movie, 0, NMOVIES);
    gather_kernel<<<2048, 256, 0, stream>>>(bk_m, movie_x, cnt_m,
                                            out_movie, 64, NMOVIES);
    gather_kernel<<<2048, 256, 0, stream>>>(bk_u, user_x, cnt_u,
                                            out_user, 64, NUSERS);

    // Exact fixup for the (statistically ~0) bucket-overflow edges.
    fixup_kernel<<<16, 256, 0, stream>>>(ovf_meta, ovf_list, user_x, movie_x,
                                         entity_x, out_user, out_movie);

    finalize_user_mfma<<<NUSERS / 64, 256, 0, stream>>>(
        user_x, cnt_u, b1, b2, BH, BL, out_user);
    finalize_movie_mfma<<<NMOVIES / 64, 256, 0, stream>>>(
        movie_x, entity_x, cnt_m, cnt_e, b1, b2, brgcn, BH, BL, out_movie);
}